// Round 1
// 96.975 us; speedup vs baseline: 1.3087x; 1.3087x over previous
//
#include <hip/hip_runtime.h>

#define IMG_H 512
#define IMG_W 512
#define N_IMG 24                          // B*C
#define NPIX (N_IMG * IMG_H * IMG_W)      // 6291456
#define ROWS_PT 4                         // rows per thread
#define NROWS 8                           // loaded rows per input
#define SLABS (IMG_H / ROWS_PT)           // 128
#define SCOLS (IMG_W / 4)                 // 128 strip-columns
#define BLOCK 256
#define NBLOCKS ((N_IMG * SLABS * SCOLS) / BLOCK)  // 1536

// Partial vmem wait + hard scheduler fence (keeps consumers below the wait).
#define VMWAIT(N)                                             \
    asm volatile("s_waitcnt vmcnt(" #N ")" ::: "memory");     \
    __builtin_amdgcn_sched_barrier(0)

// Branchless reflect for PAD=2: min(|x|, 2H-2-|x|)
__device__ __forceinline__ int reflect_b(int x) {
    int a = x < 0 ? -x : x;
    int b = 2 * IMG_H - 2 - a;
    return a < b ? a : b;
}

// Raw 16B load via volatile asm: no compiler waitcnt, immovable at IR level,
// program-ordered against the VMWAIT asms.
__device__ __forceinline__ float4 gload4(const float* p) {
    float4 r;
    asm volatile("global_load_dwordx4 %0, %1, off" : "=v"(r) : "v"(p));
    return r;
}

// Branchless fixup: raw A (cols aL..aL+3) / B (cols aR..aR+3) -> 8-float
// window (cols w0-2..w0+5, reflect-padded). Pure cndmask selects.
__device__ __forceinline__ void fix_row(float4 A, float4 B, int w0, float w[8]) {
    const bool e0 = (w0 == 0);
    const bool e5 = (w0 == 508);
    w[0] = e0 ? A.z : A.x;
    w[1] = A.y;
    w[2] = e0 ? A.x : A.z;
    w[3] = e0 ? A.y : A.w;
    w[4] = e0 ? A.z : (e5 ? B.z : B.x);
    w[5] = e0 ? A.w : (e5 ? B.w : B.y);
    w[6] = B.z;
    w[7] = e5 ? B.y : B.w;
}

#define DO_ROW(R)                                                              \
    {                                                                          \
        const float pc0 = pw[(R) + 2][2], pc1 = pw[(R) + 2][3],                \
                    pc2 = pw[(R) + 2][4], pc3 = pw[(R) + 2][5];                \
        const float gc0 = gw[(R) + 2][2], gc1 = gw[(R) + 2][3],                \
                    gc2 = gw[(R) + 2][4], gc3 = gw[(R) + 2][5];                \
        _Pragma("unroll")                                                      \
        for (int dy = 0; dy < 5; ++dy) {                                       \
            const int row = (R) + dy;                                          \
            _Pragma("unroll")                                                  \
            for (int dx = 0; dx < 5; ++dx) {                                   \
                if (dy == 2 && dx == 2) continue;                              \
                c0 += (int)((pw[row][0 + dx] < pc0) != (gw[row][0 + dx] < gc0)); \
                c1 += (int)((pw[row][1 + dx] < pc1) != (gw[row][1 + dx] < gc1)); \
                c2 += (int)((pw[row][2 + dx] < pc2) != (gw[row][2 + dx] < gc2)); \
                c3 += (int)((pw[row][3 + dx] < pc3) != (gw[row][3 + dx] < gc3)); \
            }                                                                  \
        }                                                                      \
    }

__global__ __launch_bounds__(BLOCK, 2) void census_main(
    const float* __restrict__ pred, const float* __restrict__ gt,
    unsigned int* __restrict__ ws)
{
    const int t    = blockIdx.x * BLOCK + threadIdx.x;
    const int sc   = t & (SCOLS - 1);       // strip column (consecutive lanes)
    const int rest = t >> 7;
    const int slab = rest & (SLABS - 1);
    const int img  = rest >> 7;
    const int w0   = sc * 4;
    const int h0   = slab * ROWS_PT;

    const float* __restrict__ pimg = pred + (size_t)img * IMG_H * IMG_W;
    const float* __restrict__ gimg = gt   + (size_t)img * IMG_H * IMG_W;

    // Branchless clamped in-bounds addresses (aL in [0,506], aR in [2,508]).
    const int aL = max(0, min(w0 - 2, IMG_W - 6));
    const int aR = max(2, min(w0 + 2, IMG_W - 4));

    // ---- issue ALL 32 loads (4 per row: pA,pB,gA,gB), volatile order ----
    float4 pA[NROWS], pB[NROWS], gA[NROWS], gB[NROWS];
    #pragma unroll
    for (int i = 0; i < NROWS; ++i) {
        const int ry = reflect_b(h0 - 2 + i);
        const float* prow = pimg + ry * IMG_W;
        const float* grow = gimg + ry * IMG_W;
        pA[i] = gload4(prow + aL);
        pB[i] = gload4(prow + aR);
        gA[i] = gload4(grow + aL);
        gB[i] = gload4(grow + aR);
    }
    __builtin_amdgcn_sched_barrier(0);

    float pw[NROWS][8], gw[NROWS][8];
    int c0 = 0, c1 = 0, c2 = 0, c3 = 0;

    // rows 0,1 landed (loads 0..7 retired; <=24 outstanding)
    VMWAIT(24);
    fix_row(pA[0], pB[0], w0, pw[0]); fix_row(gA[0], gB[0], w0, gw[0]);
    fix_row(pA[1], pB[1], w0, pw[1]); fix_row(gA[1], gB[1], w0, gw[1]);

    // rows 2,3,4 landed (<=12 outstanding)
    VMWAIT(12);
    fix_row(pA[2], pB[2], w0, pw[2]); fix_row(gA[2], gB[2], w0, gw[2]);
    fix_row(pA[3], pB[3], w0, pw[3]); fix_row(gA[3], gB[3], w0, gw[3]);
    fix_row(pA[4], pB[4], w0, pw[4]); fix_row(gA[4], gB[4], w0, gw[4]);
    DO_ROW(0)            // rows 5..7 still in flight

    VMWAIT(8);
    fix_row(pA[5], pB[5], w0, pw[5]); fix_row(gA[5], gB[5], w0, gw[5]);
    DO_ROW(1)

    VMWAIT(4);
    fix_row(pA[6], pB[6], w0, pw[6]); fix_row(gA[6], gB[6], w0, gw[6]);
    DO_ROW(2)

    VMWAIT(0);
    fix_row(pA[7], pB[7], w0, pw[7]); fix_row(gA[7], gB[7], w0, gw[7]);
    DO_ROW(3)

    int cnt = (c0 + c1) + (c2 + c3);

    // ---- exact integer reduction (block-local only; NO global atomics) ----
    #pragma unroll
    for (int off = 32; off > 0; off >>= 1)
        cnt += __shfl_down(cnt, off, 64);

    __shared__ int wave_sums[BLOCK / 64];
    const int lane = threadIdx.x & 63;
    const int wid  = threadIdx.x >> 6;
    if (lane == 0) wave_sums[wid] = cnt;
    __syncthreads();

    if (threadIdx.x == 0) {
        // One plain store per block to a distinct address: zero contention,
        // no fence, no readback. Wave retires immediately.
        ws[blockIdx.x] = (unsigned int)(wave_sums[0] + wave_sums[1] +
                                        wave_sums[2] + wave_sums[3]);
    }
}

// Second pass: one block sums the 1536 per-block partials and writes the mean.
// Kernel-boundary release/acquire makes census_main's stores visible here.
__global__ __launch_bounds__(BLOCK, 1) void census_reduce(
    const unsigned int* __restrict__ ws, float* __restrict__ out)
{
    unsigned int s = 0;
    #pragma unroll
    for (int i = 0; i < NBLOCKS / BLOCK; ++i)      // 6 iterations
        s += ws[threadIdx.x + i * BLOCK];

    #pragma unroll
    for (int off = 32; off > 0; off >>= 1)
        s += __shfl_down(s, off, 64);

    __shared__ unsigned int wsum[BLOCK / 64];
    const int lane = threadIdx.x & 63;
    const int wid  = threadIdx.x >> 6;
    if (lane == 0) wsum[wid] = s;
    __syncthreads();

    if (threadIdx.x == 0) {
        unsigned int tot = wsum[0] + wsum[1] + wsum[2] + wsum[3];
        out[0] = (float)((double)tot / (double)NPIX);
    }
}

extern "C" void kernel_launch(void* const* d_in, const int* in_sizes, int n_in,
                              void* d_out, int out_size, void* d_ws, size_t ws_size,
                              hipStream_t stream) {
    const float* pred = (const float*)d_in[0];
    const float* gt   = (const float*)d_in[1];
    float* out        = (float*)d_out;
    unsigned int* ws  = (unsigned int*)d_ws;   // needs NBLOCKS*4 = 6144 B

    census_main<<<NBLOCKS, BLOCK, 0, stream>>>(pred, gt, ws);
    census_reduce<<<1, BLOCK, 0, stream>>>(ws, out);
}